// Round 9
// baseline (262.275 us; speedup 1.0000x reference)
//
#include <hip/hip_runtime.h>
#include <hip/hip_bf16.h>
#include <math.h>

#define S_  2048
#define DM_ 1024

typedef unsigned short u16;
typedef __attribute__((ext_vector_type(8))) short short8;
typedef __attribute__((ext_vector_type(4))) float f32x4;

__device__ __forceinline__ u16 f2bf(float f) {
  unsigned u = __float_as_uint(f);
  u += 0x7fffu + ((u >> 16) & 1u);           // RNE
  return (u16)(u >> 16);
}
__device__ __forceinline__ float bf2f(u16 h) {
  return __uint_as_float((unsigned)h << 16);
}
__device__ __forceinline__ unsigned pack_bf2(float a, float b) {
  union { __hip_bfloat162 h2; unsigned u; } cv;
  cv.h2 = __float22bfloat162_rn(float2{a, b});   // v_cvt_pk_bf16_f32 on gfx950
  return cv.u;
}
// async global->LDS, 16B per lane. LDS dest is wave-uniform base + lane*16.
__device__ __forceinline__ void cp16(const void* g, void* l) {
  __builtin_amdgcn_global_load_lds(
      (const __attribute__((address_space(1))) unsigned*)(uintptr_t)g,
      (__attribute__((address_space(3))) unsigned*)(unsigned)(uintptr_t)l, 16, 0, 0);
}

// ---------------- fp32 -> bf16 cast ----------------
struct CastArgs { const float* src[5]; u16* dst[5]; int n[5]; };

__global__ __launch_bounds__(256) void cast_kernel(CastArgs a) {
  const int z = blockIdx.y;
  const int i = (blockIdx.x * 256 + threadIdx.x) * 8;
  if (i >= a.n[z]) return;
  const float4* s = (const float4*)(a.src[z] + i);
  float4 v0 = s[0], v1 = s[1];
  short8 r;
  r[0] = (short)f2bf(v0.x); r[1] = (short)f2bf(v0.y);
  r[2] = (short)f2bf(v0.z); r[3] = (short)f2bf(v0.w);
  r[4] = (short)f2bf(v1.x); r[5] = (short)f2bf(v1.y);
  r[6] = (short)f2bf(v1.z); r[7] = (short)f2bf(v1.w);
  *(short8*)(a.dst[z] + i) = r;
}

// ---------------- bf16 MFMA GEMM v3b: barrier-free register-direct ("flatmm-lite") ----------------
// R8 FAILED on a phantom ks dimension: a 16x16x32 MFMA consumes ONE short8/lane (k=u*8..+8,
// u=lane>>4 spans all 32 k) — the ks*32 offsets made every K-chunk get MFMA'd twice (Q,K,V ~2x).
// v3b: fa[buf][mt] / fb[buf][nt], one frag per BK=32 step, 16 MFMAs + 16 loads per kt,
// register double-buffer, x2 unroll, NO LDS, NO barriers -> compiler emits fine-grained
// vmcnt(N) per register use; loads stay in flight across the MFMA blocks (AITER pattern).
// MFMA sequence is op-for-op identical to the R7 LDS version -> bit-identical numerics.
// modes 2b/z: 0 = bf16 row-major, 1 = bf16 per-head transposed (Vt), 2 = fp32.
struct GemmArgs { const u16* A; const u16* W[3]; void* out[3]; int modes; };

__global__ __launch_bounds__(256) void gemm_mfma(GemmArgs g) {
  const int tid = threadIdx.x, lane = tid & 63, w = tid >> 6;
  const int wr = w >> 1, wc = w & 1;
  const int t = lane & 15, u = lane >> 4;
  const int z = blockIdx.z;
  const int m0 = blockIdx.y * 128, n0 = blockIdx.x * 128;

  // Lane base: frag mt at K-tile kt lives at base + mt*16*1024 + kt*32 (elements).
  const u16* __restrict__ Abase = g.A    + (size_t)(m0 + wr * 64 + t) * 1024 + u * 8;
  const u16* __restrict__ Wbase = g.W[z] + (size_t)(n0 + wc * 64 + t) * 1024 + u * 8;

  const f32x4 fzero = {0.f, 0.f, 0.f, 0.f};
  f32x4 acc[4][4];
  #pragma unroll
  for (int i = 0; i < 4; i++)
    #pragma unroll
    for (int j = 0; j < 4; j++) acc[i][j] = fzero;

  short8 fa[2][4], fb[2][4];   // [buf][mt/nt] — one short8 per 16x16x32 fragment

  // prologue: kt=0 -> buf 0
  #pragma unroll
  for (int mt = 0; mt < 4; mt++) {
    fa[0][mt] = *(const short8*)(Abase + mt * 16384);
    fb[0][mt] = *(const short8*)(Wbase + mt * 16384);
  }

  #pragma unroll 1
  for (int kt = 0; kt < 32; kt += 2) {
    // loads kt+1 -> buf 1
    #pragma unroll
    for (int mt = 0; mt < 4; mt++) {
      fa[1][mt] = *(const short8*)(Abase + (kt + 1) * 32 + mt * 16384);
      fb[1][mt] = *(const short8*)(Wbase + (kt + 1) * 32 + mt * 16384);
    }
    // MFMA on buf 0 (kt)
    #pragma unroll
    for (int mt = 0; mt < 4; mt++)
      #pragma unroll
      for (int nt = 0; nt < 4; nt++)
        acc[mt][nt] = __builtin_amdgcn_mfma_f32_16x16x32_bf16(fa[0][mt], fb[0][nt], acc[mt][nt], 0, 0, 0);
    // loads kt+2 -> buf 0
    if (kt + 2 < 32) {
      #pragma unroll
      for (int mt = 0; mt < 4; mt++) {
        fa[0][mt] = *(const short8*)(Abase + (kt + 2) * 32 + mt * 16384);
        fb[0][mt] = *(const short8*)(Wbase + (kt + 2) * 32 + mt * 16384);
      }
    }
    // MFMA on buf 1 (kt+1)
    #pragma unroll
    for (int mt = 0; mt < 4; mt++)
      #pragma unroll
      for (int nt = 0; nt < 4; nt++)
        acc[mt][nt] = __builtin_amdgcn_mfma_f32_16x16x32_bf16(fa[1][mt], fb[1][nt], acc[mt][nt], 0, 0, 0);
  }

  const int mode = (g.modes >> (2 * z)) & 3;
  const int rbase = m0 + wr * 64 + (lane >> 4) * 4;   // + mt*16 + r
  const int cbase = n0 + wc * 64 + (lane & 15);       // + nt*16
  if (mode == 0) {
    u16* O = (u16*)g.out[z];
    #pragma unroll
    for (int mt = 0; mt < 4; mt++)
      #pragma unroll
      for (int nt = 0; nt < 4; nt++)
        #pragma unroll
        for (int r = 0; r < 4; r++)
          O[(size_t)(rbase + mt * 16 + r) * 1024 + cbase + nt * 16] = f2bf(acc[mt][nt][r]);
  } else if (mode == 1) {
    u16* O = (u16*)g.out[z];
    #pragma unroll
    for (int mt = 0; mt < 4; mt++)
      #pragma unroll
      for (int nt = 0; nt < 4; nt++) {
        int gr = rbase + mt * 16;
        int b = gr >> 11, s0 = gr & (S_ - 1);
        int gc = cbase + nt * 16;
        int h = gc >> 6, d = gc & 63;
        ushort4 v;
        v.x = f2bf(acc[mt][nt][0]); v.y = f2bf(acc[mt][nt][1]);
        v.z = f2bf(acc[mt][nt][2]); v.w = f2bf(acc[mt][nt][3]);
        *(ushort4*)&O[(size_t)((b * 16 + h) * 64 + d) * 2048 + s0] = v;
      }
  } else {
    float* O = (float*)g.out[z];
    #pragma unroll
    for (int mt = 0; mt < 4; mt++)
      #pragma unroll
      for (int nt = 0; nt < 4; nt++)
        #pragma unroll
        for (int r = 0; r < 4; r++)
          O[(size_t)(rbase + mt * 16 + r) * 1024 + cbase + nt * 16] = acc[mt][nt][r];
  }
}

// ---------------- RoPE in-place on bf16 q/k; q PRE-SCALED by 0.125*log2(e) ----------------
__global__ __launch_bounds__(256) void rope_kernel(u16* qb, u16* kb, const int* __restrict__ tp) {
  const int isq = (blockIdx.y == 0);
  u16* p = isq ? qb : kb;
  const float outscale = isq ? 0.18033688011112042f : 1.0f;   // 0.125 * log2(e)
  const int i = (blockIdx.x * 256 + threadIdx.x) * 8;
  const int s = (i >> 10) & (S_ - 1);
  const int d = i & 63;
  const float pos = (float)tp[s];
  short8 v = *(short8*)(p + i);
  #pragma unroll
  for (int j = 0; j < 4; j++) {
    float inv = exp2f(-(float)(d + 2 * j) * 0.20762050593046439f);  // log2(10000)/64
    float phi = pos * inv;
    float sn, cs;
    sincosf(phi, &sn, &cs);
    float xe = bf2f((u16)v[2 * j]), xo = bf2f((u16)v[2 * j + 1]);
    v[2 * j]     = (short)f2bf((xe * cs - xo * sn) * outscale);
    v[2 * j + 1] = (short)f2bf((xe * sn + xo * cs) * outscale);
  }
  *(short8*)(p + i) = v;
}

// ---------------- MFMA flash attention v4 (R7-proven): paired q-tiles, 8-wave blocks ----------------
__global__ __launch_bounds__(512, 4) void attn_mfma(const u16* __restrict__ qb, const u16* __restrict__ kb,
                                                    const u16* __restrict__ vt, u16* __restrict__ ab) {
  __shared__ __align__(16) u16 Qs[2][4096];
  __shared__ __align__(16) u16 Ks[2][4096];
  __shared__ __align__(16) u16 Vs[2][4096];

  const int tid = threadIdx.x, lane = tid & 63, w = tid >> 6;
  const int v = w & 3, g = w >> 2;
  const int t = lane & 15, u = lane >> 4;
  const int bh = blockIdx.y, b = bh >> 4, h = bh & 15;
  const int i = blockIdx.x;              // 0..15
  const int qa = 31 - i;                 // tile A (long)
  const int qbt = i;                     // tile B (short)
  const int nk = 32 - i;                 // K/V stream length in 64-key tiles
  const size_t qkb = (size_t)b * S_ * 1024 + h * 64;
  const size_t vtb = (size_t)bh * 64 * 2048;

  {
    const int qtile = g ? qbt : qa;
    cp16(qb + qkb + (size_t)(qtile * 64 + lane) * 1024 + v * 8,       (char*)Qs[g] + v * 1024);
    cp16(qb + qkb + (size_t)(qtile * 64 + lane) * 1024 + (v + 4) * 8, (char*)Qs[g] + 4096 + v * 1024);
  }
  cp16(kb + qkb + (size_t)lane * 1024 + w * 8, (char*)Ks[0] + w * 1024);
  cp16(vt + vtb + (size_t)lane * 2048 + w * 8, (char*)Vs[0] + w * 1024);
  __syncthreads();

  short8 aqA[2], aqP[2];
  #pragma unroll
  for (int ks = 0; ks < 2; ks++) {
    aqA[ks] = *(const short8*)((const char*)Qs[0] + (ks * 4 + u) * 1024 + (v * 16 + t) * 16);
    short8 bq = *(const short8*)((const char*)Qs[1] + (ks * 4 + u) * 1024 + (v * 16 + t) * 16);
    aqP[ks] = g ? bq : aqA[ks];
  }

  const f32x4 fzero = {0.f, 0.f, 0.f, 0.f};
  f32x4 oPrim[4], oSec[4];
  #pragma unroll
  for (int ct = 0; ct < 4; ct++) { oPrim[ct] = fzero; oSec[ct] = fzero; }
  float rsumP = 0.f, rsumS = 0.f;

  const int qprim = g ? qbt : qa;
  const int qrowP = qprim * 64 + v * 16 + t;
  const int qrowA = qa * 64 + v * 16 + t;

  for (int kt = 0; kt < nk; kt++) {
    const int cur = kt & 1, nxt = cur ^ 1;
    if (kt + 1 < nk) {
      cp16(kb + qkb + (size_t)((kt + 1) * 64 + lane) * 1024 + w * 8, (char*)Ks[nxt] + w * 1024);
      cp16(vt + vtb + (size_t)lane * 2048 + (kt + 1) * 64 + w * 8,   (char*)Vs[nxt] + w * 1024);
    }

    if (kt <= qbt) {
      f32x4 st[4] = {fzero, fzero, fzero, fzero};
      #pragma unroll
      for (int ks = 0; ks < 2; ks++)
        #pragma unroll
        for (int ct = 0; ct < 4; ct++) {
          short8 kf = *(const short8*)((const char*)Ks[cur] + (ks * 4 + u) * 1024 + (ct * 16 + t) * 16);
          st[ct] = __builtin_amdgcn_mfma_f32_16x16x32_bf16(kf, aqP[ks], st[ct], 0, 0, 0);
        }

      unsigned pb2[4][2];
      const bool diag = (kt == qprim);
      #pragma unroll
      for (int ct = 0; ct < 4; ct++) {
        float p[4];
        #pragma unroll
        for (int r = 0; r < 4; r++) {
          int key = kt * 64 + ct * 16 + 4 * u + r;
          float pv = exp2f(st[ct][r]);
          p[r] = (diag && key > qrowP) ? 0.f : pv;
          rsumP += p[r];
        }
        pb2[ct][0] = pack_bf2(p[0], p[1]);
        pb2[ct][1] = pack_bf2(p[2], p[3]);
      }

      #pragma unroll
      for (int ks = 0; ks < 2; ks++) {
        union { short8 s8; int i4[4]; } pf;
        #pragma unroll
        for (int jj = 0; jj < 4; jj++) {
          int src = 32 * (u & 1) + 16 * (jj >> 1) + t;
          int v0 = __shfl((int)pb2[ks * 2][jj & 1], src, 64);
          int v1 = __shfl((int)pb2[ks * 2 + 1][jj & 1], src, 64);
          pf.i4[jj] = (u >> 1) ? v1 : v0;
        }
        #pragma unroll
        for (int ct = 0; ct < 4; ct++) {
          short8 vf = *(const short8*)((const char*)Vs[cur] + (ks * 4 + u) * 1024 + (ct * 16 + t) * 16);
          oPrim[ct] = __builtin_amdgcn_mfma_f32_16x16x32_bf16(vf, pf.s8, oPrim[ct], 0, 0, 0);
        }
      }
    } else {
      f32x4 st2[2] = {fzero, fzero};
      #pragma unroll
      for (int ks = 0; ks < 2; ks++)
        #pragma unroll
        for (int c = 0; c < 2; c++) {
          short8 kf = *(const short8*)((const char*)Ks[cur] + (ks * 4 + u) * 1024 + ((2 * g + c) * 16 + t) * 16);
          st2[c] = __builtin_amdgcn_mfma_f32_16x16x32_bf16(kf, aqA[ks], st2[c], 0, 0, 0);
        }

      unsigned ph[2][2];
      float rs = 0.f;
      const bool diag = (kt == qa);
      #pragma unroll
      for (int c = 0; c < 2; c++) {
        float p[4];
        #pragma unroll
        for (int r = 0; r < 4; r++) {
          int key = kt * 64 + (2 * g + c) * 16 + 4 * u + r;
          float pv = exp2f(st2[c][r]);
          p[r] = (diag && key > qrowA) ? 0.f : pv;
          rs += p[r];
        }
        ph[c][0] = pack_bf2(p[0], p[1]);
        ph[c][1] = pack_bf2(p[2], p[3]);
      }

      union { short8 s8; int i4[4]; } pf;
      #pragma unroll
      for (int jj = 0; jj < 4; jj++) {
        int src = 32 * (u & 1) + 16 * (jj >> 1) + t;
        int v0 = __shfl((int)ph[0][jj & 1], src, 64);
        int v1 = __shfl((int)ph[1][jj & 1], src, 64);
        pf.i4[jj] = (u >> 1) ? v1 : v0;
      }
      if (g) {
        rsumS += rs;
        #pragma unroll
        for (int ct = 0; ct < 4; ct++) {
          short8 vf = *(const short8*)((const char*)Vs[cur] + (4 + u) * 1024 + (ct * 16 + t) * 16);
          oSec[ct] = __builtin_amdgcn_mfma_f32_16x16x32_bf16(vf, pf.s8, oSec[ct], 0, 0, 0);
        }
      } else {
        rsumP += rs;
        #pragma unroll
        for (int ct = 0; ct < 4; ct++) {
          short8 vf = *(const short8*)((const char*)Vs[cur] + u * 1024 + (ct * 16 + t) * 16);
          oPrim[ct] = __builtin_amdgcn_mfma_f32_16x16x32_bf16(vf, pf.s8, oPrim[ct], 0, 0, 0);
        }
      }
    }
    __syncthreads();
  }

  // ---- epilogue ----
  float* dmpO = (float*)Ks;
  float* dmpR = (float*)Vs;
  if (g) {
    #pragma unroll
    for (int ct = 0; ct < 4; ct++)
      *(f32x4*)&dmpO[(size_t)(v * 64 + lane) * 16 + ct * 4] = oSec[ct];
    dmpR[v * 64 + lane] = rsumS;
    float rs = rsumP;
    rs += __shfl_xor(rs, 16, 64);
    rs += __shfl_xor(rs, 32, 64);
    const float inv = 1.0f / rs;
    #pragma unroll
    for (int ct = 0; ct < 4; ct++) {
      ushort4 vv;
      vv.x = f2bf(oPrim[ct][0] * inv); vv.y = f2bf(oPrim[ct][1] * inv);
      vv.z = f2bf(oPrim[ct][2] * inv); vv.w = f2bf(oPrim[ct][3] * inv);
      *(ushort4*)&ab[((size_t)b * S_ + qrowP) * 1024 + h * 64 + ct * 16 + 4 * u] = vv;
    }
  }
  __syncthreads();
  if (!g) {
    #pragma unroll
    for (int ct = 0; ct < 4; ct++) {
      f32x4 add = *(const f32x4*)&dmpO[(size_t)(v * 64 + lane) * 16 + ct * 4];
      oPrim[ct] += add;
    }
    float rs = rsumP + dmpR[v * 64 + lane];
    rs += __shfl_xor(rs, 16, 64);
    rs += __shfl_xor(rs, 32, 64);
    const float inv = 1.0f / rs;
    #pragma unroll
    for (int ct = 0; ct < 4; ct++) {
      ushort4 vv;
      vv.x = f2bf(oPrim[ct][0] * inv); vv.y = f2bf(oPrim[ct][1] * inv);
      vv.z = f2bf(oPrim[ct][2] * inv); vv.w = f2bf(oPrim[ct][3] * inv);
      *(ushort4*)&ab[((size_t)b * S_ + qrowA) * 1024 + h * 64 + ct * 16 + 4 * u] = vv;
    }
  }
}

extern "C" void kernel_launch(void* const* d_in, const int* in_sizes, int n_in,
                              void* d_out, int out_size, void* d_ws, size_t ws_size,
                              hipStream_t stream) {
  const float* x  = (const float*)d_in[0];
  const float* Wq = (const float*)d_in[1];
  const float* Wk = (const float*)d_in[2];
  const float* Wv = (const float*)d_in[3];
  const float* Wo = (const float*)d_in[4];
  const int*   tp = (const int*)d_in[5];
  float* out = (float*)d_out;

  char* ws = (char*)d_ws;
  u16* xb  = (u16*)(ws);                       // 8 MB
  u16* wqb = (u16*)(ws + (8 << 20));           // 2 MB each
  u16* wkb = (u16*)(ws + (10 << 20));
  u16* wvb = (u16*)(ws + (12 << 20));
  u16* wob = (u16*)(ws + (14 << 20));
  u16* qbuf = (u16*)(ws + (16 << 20));         // 8 MB
  u16* kbuf = (u16*)(ws + (24 << 20));
  u16* vtb  = (u16*)(ws + (32 << 20));
  u16* abuf = (u16*)(ws + (40 << 20));

  CastArgs ca;
  ca.src[0] = x;  ca.dst[0] = xb;  ca.n[0] = 2 * S_ * DM_;
  ca.src[1] = Wq; ca.dst[1] = wqb; ca.n[1] = DM_ * DM_;
  ca.src[2] = Wk; ca.dst[2] = wkb; ca.n[2] = DM_ * DM_;
  ca.src[3] = Wv; ca.dst[3] = wvb; ca.n[3] = DM_ * DM_;
  ca.src[4] = Wo; ca.dst[4] = wob; ca.n[4] = DM_ * DM_;
  cast_kernel<<<dim3(2048, 5), 256, 0, stream>>>(ca);

  GemmArgs gq;
  gq.A = xb;
  gq.W[0] = wqb; gq.W[1] = wkb; gq.W[2] = wvb;
  gq.out[0] = qbuf; gq.out[1] = kbuf; gq.out[2] = vtb;
  gq.modes = (1 << 4);                         // z0,z1: bf16; z2: Vt
  gemm_mfma<<<dim3(8, 32, 3), 256, 0, stream>>>(gq);

  rope_kernel<<<dim3(2048, 2), 256, 0, stream>>>(qbuf, kbuf, tp);

  attn_mfma<<<dim3(16, 32), 512, 0, stream>>>(qbuf, kbuf, vtb, abuf);

  GemmArgs go;
  go.A = abuf;
  go.W[0] = wob; go.W[1] = wob; go.W[2] = wob;
  go.out[0] = out; go.out[1] = out; go.out[2] = out;
  go.modes = 2;                                // fp32 out
  gemm_mfma<<<dim3(8, 32, 1), 256, 0, stream>>>(go);
}

// Round 10
// 245.129 us; speedup vs baseline: 1.0699x; 1.0699x over previous
//
#include <hip/hip_runtime.h>
#include <hip/hip_bf16.h>
#include <math.h>

#define S_  2048
#define DM_ 1024

typedef unsigned short u16;
typedef __attribute__((ext_vector_type(8))) short short8;
typedef __attribute__((ext_vector_type(4))) float f32x4;

__device__ __forceinline__ u16 f2bf(float f) {
  unsigned u = __float_as_uint(f);
  u += 0x7fffu + ((u >> 16) & 1u);           // RNE
  return (u16)(u >> 16);
}
__device__ __forceinline__ float bf2f(u16 h) {
  return __uint_as_float((unsigned)h << 16);
}
__device__ __forceinline__ unsigned pack_bf2(float a, float b) {
  union { __hip_bfloat162 h2; unsigned u; } cv;
  cv.h2 = __float22bfloat162_rn(float2{a, b});   // v_cvt_pk_bf16_f32 on gfx950
  return cv.u;
}
// async global->LDS, 16B per lane. LDS dest is wave-uniform base + lane*16.
__device__ __forceinline__ void cp16(const void* g, void* l) {
  __builtin_amdgcn_global_load_lds(
      (const __attribute__((address_space(1))) unsigned*)(uintptr_t)g,
      (__attribute__((address_space(3))) unsigned*)(unsigned)(uintptr_t)l, 16, 0, 0);
}

// ---------------- fp32 -> bf16 cast ----------------
struct CastArgs { const float* src[5]; u16* dst[5]; int n[5]; };

__global__ __launch_bounds__(256) void cast_kernel(CastArgs a) {
  const int z = blockIdx.y;
  const int i = (blockIdx.x * 256 + threadIdx.x) * 8;
  if (i >= a.n[z]) return;
  const float4* s = (const float4*)(a.src[z] + i);
  float4 v0 = s[0], v1 = s[1];
  short8 r;
  r[0] = (short)f2bf(v0.x); r[1] = (short)f2bf(v0.y);
  r[2] = (short)f2bf(v0.z); r[3] = (short)f2bf(v0.w);
  r[4] = (short)f2bf(v1.x); r[5] = (short)f2bf(v1.y);
  r[6] = (short)f2bf(v1.z); r[7] = (short)f2bf(v1.w);
  *(short8*)(a.dst[z] + i) = r;
}

// ---------------- bf16 MFMA GEMM v4: hybrid A-LDS + B-register ----------------
// R7's 64us sits near the ds_read throughput floor (8 b128/wave/round -> ~1130 cyc/CU/round
// at 85 B/cyc vs MFMA 933) — cutting LDS traffic is the lever, not more pipelining.
// R9's all-register flatmm failed on half-round prefetch distance (80-160 cyc vs 200-900 load
// latency) + 16 loads/round. Hybrid: A staged in LDS (shared by 2 waves, cp16 dbuf, R7-proven
// layout/rhythm), B direct global->register (R9-proven addressing), register dbuf with
// FULL-ROUND prefetch distance: fb[kt+1] issued at round start, consumed after next barrier.
// ds_read halves (8->4/wave/round), staging halves, B loads ~800cyc old at barrier drain.
// modes 2b/z: 0 = bf16 row-major, 1 = bf16 per-head transposed (Vt), 2 = fp32.
struct GemmArgs { const u16* A; const u16* W[3]; void* out[3]; int modes; };

__global__ __launch_bounds__(256) void gemm_mfma(GemmArgs g) {
  __shared__ __align__(16) u16 As[2][4096];
  const int tid = threadIdx.x, lane = tid & 63, w = tid >> 6;
  const int wr = w >> 1, wc = w & 1;
  const int t = lane & 15, u = lane >> 4;
  const int z = blockIdx.z;
  const int m0 = blockIdx.y * 128, n0 = blockIdx.x * 128;

  const f32x4 fzero = {0.f, 0.f, 0.f, 0.f};
  f32x4 acc[4][4];
  #pragma unroll
  for (int i = 0; i < 4; i++)
    #pragma unroll
    for (int j = 0; j < 4; j++) acc[i][j] = fzero;

  const int c0 = tid >> 7;            // A staging: chunk 0..1 (+2 for second cp16)
  const int rs = tid & 127;           // A staging: row 0..127
  const int fq = u * 2048;            // A frag chunk byte offset
  const int fr = t * 16;              // A frag row byte offset

  const u16* Arow  = g.A + (size_t)(m0 + rs) * 1024;
  // B fragment lane base (R9-proven): row n0+wc*64+nt*16+t, k-chunk u; + kt*32 + nt*16*1024.
  const u16* Wfrag = g.W[z] + (size_t)(n0 + wc * 64 + t) * 1024 + u * 8;

  short8 fb[2][4];                    // B register double-buffer

  // prologue: stage A tile 0, load B frags 0
  cp16(Arow + c0 * 8,       (char*)As[0] + w * 1024);
  cp16(Arow + (c0 + 2) * 8, (char*)As[0] + 4096 + w * 1024);
  #pragma unroll
  for (int nt = 0; nt < 4; nt++)
    fb[0][nt] = *(const short8*)(Wfrag + nt * 16384);
  __syncthreads();

  for (int kt = 0; kt < 32; kt++) {
    const int cur = kt & 1, nxt = cur ^ 1;
    if (kt < 31) {
      const int k1 = (kt + 1) * 32;
      cp16(Arow + k1 + c0 * 8,       (char*)As[nxt] + w * 1024);
      cp16(Arow + k1 + (c0 + 2) * 8, (char*)As[nxt] + 4096 + w * 1024);
      #pragma unroll
      for (int nt = 0; nt < 4; nt++)
        fb[nxt][nt] = *(const short8*)(Wfrag + k1 + nt * 16384);
    }

    short8 af[4];
    #pragma unroll
    for (int mt = 0; mt < 4; mt++)
      af[mt] = *(const short8*)((const char*)As[cur] + fq + (wr * 64 + mt * 16) * 16 + fr);
    #pragma unroll
    for (int mt = 0; mt < 4; mt++)
      #pragma unroll
      for (int nt = 0; nt < 4; nt++)
        acc[mt][nt] = __builtin_amdgcn_mfma_f32_16x16x32_bf16(af[mt], fb[cur][nt], acc[mt][nt], 0, 0, 0);
    __syncthreads();
  }

  const int mode = (g.modes >> (2 * z)) & 3;
  const int rbase = m0 + wr * 64 + (lane >> 4) * 4;   // + mt*16 + r
  const int cbase = n0 + wc * 64 + (lane & 15);       // + nt*16
  if (mode == 0) {
    u16* O = (u16*)g.out[z];
    #pragma unroll
    for (int mt = 0; mt < 4; mt++)
      #pragma unroll
      for (int nt = 0; nt < 4; nt++)
        #pragma unroll
        for (int r = 0; r < 4; r++)
          O[(size_t)(rbase + mt * 16 + r) * 1024 + cbase + nt * 16] = f2bf(acc[mt][nt][r]);
  } else if (mode == 1) {
    // Vt[b][h][d][s], 4 consecutive s per store
    u16* O = (u16*)g.out[z];
    #pragma unroll
    for (int mt = 0; mt < 4; mt++)
      #pragma unroll
      for (int nt = 0; nt < 4; nt++) {
        int gr = rbase + mt * 16;
        int b = gr >> 11, s0 = gr & (S_ - 1);
        int gc = cbase + nt * 16;
        int h = gc >> 6, d = gc & 63;
        ushort4 v;
        v.x = f2bf(acc[mt][nt][0]); v.y = f2bf(acc[mt][nt][1]);
        v.z = f2bf(acc[mt][nt][2]); v.w = f2bf(acc[mt][nt][3]);
        *(ushort4*)&O[(size_t)((b * 16 + h) * 64 + d) * 2048 + s0] = v;
      }
  } else {
    float* O = (float*)g.out[z];
    #pragma unroll
    for (int mt = 0; mt < 4; mt++)
      #pragma unroll
      for (int nt = 0; nt < 4; nt++)
        #pragma unroll
        for (int r = 0; r < 4; r++)
          O[(size_t)(rbase + mt * 16 + r) * 1024 + cbase + nt * 16] = acc[mt][nt][r];
  }
}

// ---------------- RoPE in-place on bf16 q/k; q PRE-SCALED by 0.125*log2(e) ----------------
__global__ __launch_bounds__(256) void rope_kernel(u16* qb, u16* kb, const int* __restrict__ tp) {
  const int isq = (blockIdx.y == 0);
  u16* p = isq ? qb : kb;
  const float outscale = isq ? 0.18033688011112042f : 1.0f;   // 0.125 * log2(e)
  const int i = (blockIdx.x * 256 + threadIdx.x) * 8;
  const int s = (i >> 10) & (S_ - 1);
  const int d = i & 63;
  const float pos = (float)tp[s];
  short8 v = *(short8*)(p + i);
  #pragma unroll
  for (int j = 0; j < 4; j++) {
    float inv = exp2f(-(float)(d + 2 * j) * 0.20762050593046439f);  // log2(10000)/64
    float phi = pos * inv;
    float sn, cs;
    sincosf(phi, &sn, &cs);
    float xe = bf2f((u16)v[2 * j]), xo = bf2f((u16)v[2 * j + 1]);
    v[2 * j]     = (short)f2bf((xe * cs - xo * sn) * outscale);
    v[2 * j + 1] = (short)f2bf((xe * sn + xo * cs) * outscale);
  }
  *(short8*)(p + i) = v;
}

// ---------------- MFMA flash attention v4 (R7-proven): paired q-tiles, 8-wave blocks ----------------
__global__ __launch_bounds__(512, 4) void attn_mfma(const u16* __restrict__ qb, const u16* __restrict__ kb,
                                                    const u16* __restrict__ vt, u16* __restrict__ ab) {
  __shared__ __align__(16) u16 Qs[2][4096];
  __shared__ __align__(16) u16 Ks[2][4096];
  __shared__ __align__(16) u16 Vs[2][4096];

  const int tid = threadIdx.x, lane = tid & 63, w = tid >> 6;
  const int v = w & 3, g = w >> 2;
  const int t = lane & 15, u = lane >> 4;
  const int bh = blockIdx.y, b = bh >> 4, h = bh & 15;
  const int i = blockIdx.x;              // 0..15
  const int qa = 31 - i;                 // tile A (long)
  const int qbt = i;                     // tile B (short)
  const int nk = 32 - i;                 // K/V stream length in 64-key tiles
  const size_t qkb = (size_t)b * S_ * 1024 + h * 64;
  const size_t vtb = (size_t)bh * 64 * 2048;

  {
    const int qtile = g ? qbt : qa;
    cp16(qb + qkb + (size_t)(qtile * 64 + lane) * 1024 + v * 8,       (char*)Qs[g] + v * 1024);
    cp16(qb + qkb + (size_t)(qtile * 64 + lane) * 1024 + (v + 4) * 8, (char*)Qs[g] + 4096 + v * 1024);
  }
  cp16(kb + qkb + (size_t)lane * 1024 + w * 8, (char*)Ks[0] + w * 1024);
  cp16(vt + vtb + (size_t)lane * 2048 + w * 8, (char*)Vs[0] + w * 1024);
  __syncthreads();

  short8 aqA[2], aqP[2];
  #pragma unroll
  for (int ks = 0; ks < 2; ks++) {
    aqA[ks] = *(const short8*)((const char*)Qs[0] + (ks * 4 + u) * 1024 + (v * 16 + t) * 16);
    short8 bq = *(const short8*)((const char*)Qs[1] + (ks * 4 + u) * 1024 + (v * 16 + t) * 16);
    aqP[ks] = g ? bq : aqA[ks];
  }

  const f32x4 fzero = {0.f, 0.f, 0.f, 0.f};
  f32x4 oPrim[4], oSec[4];
  #pragma unroll
  for (int ct = 0; ct < 4; ct++) { oPrim[ct] = fzero; oSec[ct] = fzero; }
  float rsumP = 0.f, rsumS = 0.f;

  const int qprim = g ? qbt : qa;
  const int qrowP = qprim * 64 + v * 16 + t;
  const int qrowA = qa * 64 + v * 16 + t;

  for (int kt = 0; kt < nk; kt++) {
    const int cur = kt & 1, nxt = cur ^ 1;
    if (kt + 1 < nk) {
      cp16(kb + qkb + (size_t)((kt + 1) * 64 + lane) * 1024 + w * 8, (char*)Ks[nxt] + w * 1024);
      cp16(vt + vtb + (size_t)lane * 2048 + (kt + 1) * 64 + w * 8,   (char*)Vs[nxt] + w * 1024);
    }

    if (kt <= qbt) {
      f32x4 st[4] = {fzero, fzero, fzero, fzero};
      #pragma unroll
      for (int ks = 0; ks < 2; ks++)
        #pragma unroll
        for (int ct = 0; ct < 4; ct++) {
          short8 kf = *(const short8*)((const char*)Ks[cur] + (ks * 4 + u) * 1024 + (ct * 16 + t) * 16);
          st[ct] = __builtin_amdgcn_mfma_f32_16x16x32_bf16(kf, aqP[ks], st[ct], 0, 0, 0);
        }

      unsigned pb2[4][2];
      const bool diag = (kt == qprim);
      #pragma unroll
      for (int ct = 0; ct < 4; ct++) {
        float p[4];
        #pragma unroll
        for (int r = 0; r < 4; r++) {
          int key = kt * 64 + ct * 16 + 4 * u + r;
          float pv = exp2f(st[ct][r]);
          p[r] = (diag && key > qrowP) ? 0.f : pv;
          rsumP += p[r];
        }
        pb2[ct][0] = pack_bf2(p[0], p[1]);
        pb2[ct][1] = pack_bf2(p[2], p[3]);
      }

      #pragma unroll
      for (int ks = 0; ks < 2; ks++) {
        union { short8 s8; int i4[4]; } pf;
        #pragma unroll
        for (int jj = 0; jj < 4; jj++) {
          int src = 32 * (u & 1) + 16 * (jj >> 1) + t;
          int v0 = __shfl((int)pb2[ks * 2][jj & 1], src, 64);
          int v1 = __shfl((int)pb2[ks * 2 + 1][jj & 1], src, 64);
          pf.i4[jj] = (u >> 1) ? v1 : v0;
        }
        #pragma unroll
        for (int ct = 0; ct < 4; ct++) {
          short8 vf = *(const short8*)((const char*)Vs[cur] + (ks * 4 + u) * 1024 + (ct * 16 + t) * 16);
          oPrim[ct] = __builtin_amdgcn_mfma_f32_16x16x32_bf16(vf, pf.s8, oPrim[ct], 0, 0, 0);
        }
      }
    } else {
      f32x4 st2[2] = {fzero, fzero};
      #pragma unroll
      for (int ks = 0; ks < 2; ks++)
        #pragma unroll
        for (int c = 0; c < 2; c++) {
          short8 kf = *(const short8*)((const char*)Ks[cur] + (ks * 4 + u) * 1024 + ((2 * g + c) * 16 + t) * 16);
          st2[c] = __builtin_amdgcn_mfma_f32_16x16x32_bf16(kf, aqA[ks], st2[c], 0, 0, 0);
        }

      unsigned ph[2][2];
      float rs = 0.f;
      const bool diag = (kt == qa);
      #pragma unroll
      for (int c = 0; c < 2; c++) {
        float p[4];
        #pragma unroll
        for (int r = 0; r < 4; r++) {
          int key = kt * 64 + (2 * g + c) * 16 + 4 * u + r;
          float pv = exp2f(st2[c][r]);
          p[r] = (diag && key > qrowA) ? 0.f : pv;
          rs += p[r];
        }
        ph[c][0] = pack_bf2(p[0], p[1]);
        ph[c][1] = pack_bf2(p[2], p[3]);
      }

      union { short8 s8; int i4[4]; } pf;
      #pragma unroll
      for (int jj = 0; jj < 4; jj++) {
        int src = 32 * (u & 1) + 16 * (jj >> 1) + t;
        int v0 = __shfl((int)ph[0][jj & 1], src, 64);
        int v1 = __shfl((int)ph[1][jj & 1], src, 64);
        pf.i4[jj] = (u >> 1) ? v1 : v0;
      }
      if (g) {
        rsumS += rs;
        #pragma unroll
        for (int ct = 0; ct < 4; ct++) {
          short8 vf = *(const short8*)((const char*)Vs[cur] + (4 + u) * 1024 + (ct * 16 + t) * 16);
          oSec[ct] = __builtin_amdgcn_mfma_f32_16x16x32_bf16(vf, pf.s8, oSec[ct], 0, 0, 0);
        }
      } else {
        rsumP += rs;
        #pragma unroll
        for (int ct = 0; ct < 4; ct++) {
          short8 vf = *(const short8*)((const char*)Vs[cur] + u * 1024 + (ct * 16 + t) * 16);
          oPrim[ct] = __builtin_amdgcn_mfma_f32_16x16x32_bf16(vf, pf.s8, oPrim[ct], 0, 0, 0);
        }
      }
    }
    __syncthreads();
  }

  // ---- epilogue ----
  float* dmpO = (float*)Ks;
  float* dmpR = (float*)Vs;
  if (g) {
    #pragma unroll
    for (int ct = 0; ct < 4; ct++)
      *(f32x4*)&dmpO[(size_t)(v * 64 + lane) * 16 + ct * 4] = oSec[ct];
    dmpR[v * 64 + lane] = rsumS;
    float rs = rsumP;
    rs += __shfl_xor(rs, 16, 64);
    rs += __shfl_xor(rs, 32, 64);
    const float inv = 1.0f / rs;
    #pragma unroll
    for (int ct = 0; ct < 4; ct++) {
      ushort4 vv;
      vv.x = f2bf(oPrim[ct][0] * inv); vv.y = f2bf(oPrim[ct][1] * inv);
      vv.z = f2bf(oPrim[ct][2] * inv); vv.w = f2bf(oPrim[ct][3] * inv);
      *(ushort4*)&ab[((size_t)b * S_ + qrowP) * 1024 + h * 64 + ct * 16 + 4 * u] = vv;
    }
  }
  __syncthreads();
  if (!g) {
    #pragma unroll
    for (int ct = 0; ct < 4; ct++) {
      f32x4 add = *(const f32x4*)&dmpO[(size_t)(v * 64 + lane) * 16 + ct * 4];
      oPrim[ct] += add;
    }
    float rs = rsumP + dmpR[v * 64 + lane];
    rs += __shfl_xor(rs, 16, 64);
    rs += __shfl_xor(rs, 32, 64);
    const float inv = 1.0f / rs;
    #pragma unroll
    for (int ct = 0; ct < 4; ct++) {
      ushort4 vv;
      vv.x = f2bf(oPrim[ct][0] * inv); vv.y = f2bf(oPrim[ct][1] * inv);
      vv.z = f2bf(oPrim[ct][2] * inv); vv.w = f2bf(oPrim[ct][3] * inv);
      *(ushort4*)&ab[((size_t)b * S_ + qrowA) * 1024 + h * 64 + ct * 16 + 4 * u] = vv;
    }
  }
}

extern "C" void kernel_launch(void* const* d_in, const int* in_sizes, int n_in,
                              void* d_out, int out_size, void* d_ws, size_t ws_size,
                              hipStream_t stream) {
  const float* x  = (const float*)d_in[0];
  const float* Wq = (const float*)d_in[1];
  const float* Wk = (const float*)d_in[2];
  const float* Wv = (const float*)d_in[3];
  const float* Wo = (const float*)d_in[4];
  const int*   tp = (const int*)d_in[5];
  float* out = (float*)d_out;

  char* ws = (char*)d_ws;
  u16* xb  = (u16*)(ws);                       // 8 MB
  u16* wqb = (u16*)(ws + (8 << 20));           // 2 MB each
  u16* wkb = (u16*)(ws + (10 << 20));
  u16* wvb = (u16*)(ws + (12 << 20));
  u16* wob = (u16*)(ws + (14 << 20));
  u16* qbuf = (u16*)(ws + (16 << 20));         // 8 MB
  u16* kbuf = (u16*)(ws + (24 << 20));
  u16* vtb  = (u16*)(ws + (32 << 20));
  u16* abuf = (u16*)(ws + (40 << 20));

  CastArgs ca;
  ca.src[0] = x;  ca.dst[0] = xb;  ca.n[0] = 2 * S_ * DM_;
  ca.src[1] = Wq; ca.dst[1] = wqb; ca.n[1] = DM_ * DM_;
  ca.src[2] = Wk; ca.dst[2] = wkb; ca.n[2] = DM_ * DM_;
  ca.src[3] = Wv; ca.dst[3] = wvb; ca.n[3] = DM_ * DM_;
  ca.src[4] = Wo; ca.dst[4] = wob; ca.n[4] = DM_ * DM_;
  cast_kernel<<<dim3(2048, 5), 256, 0, stream>>>(ca);

  GemmArgs gq;
  gq.A = xb;
  gq.W[0] = wqb; gq.W[1] = wkb; gq.W[2] = wvb;
  gq.out[0] = qbuf; gq.out[1] = kbuf; gq.out[2] = vtb;
  gq.modes = (1 << 4);                         // z0,z1: bf16; z2: Vt
  gemm_mfma<<<dim3(8, 32, 3), 256, 0, stream>>>(gq);

  rope_kernel<<<dim3(2048, 2), 256, 0, stream>>>(qbuf, kbuf, tp);

  attn_mfma<<<dim3(16, 32), 512, 0, stream>>>(qbuf, kbuf, vtb, abuf);

  GemmArgs go;
  go.A = abuf;
  go.W[0] = wob; go.W[1] = wob; go.W[2] = wob;
  go.out[0] = out; go.out[1] = out; go.out[2] = out;
  go.modes = 2;                                // fp32 out
  gemm_mfma<<<dim3(8, 32, 1), 256, 0, stream>>>(go);
}

// Round 11
// 227.775 us; speedup vs baseline: 1.1515x; 1.0762x over previous
//
#include <hip/hip_runtime.h>
#include <hip/hip_bf16.h>
#include <math.h>

#define S_  2048
#define DM_ 1024

typedef unsigned short u16;
typedef __attribute__((ext_vector_type(8))) short short8;
typedef __attribute__((ext_vector_type(4))) float f32x4;

__device__ __forceinline__ u16 f2bf(float f) {
  unsigned u = __float_as_uint(f);
  u += 0x7fffu + ((u >> 16) & 1u);           // RNE
  return (u16)(u >> 16);
}
__device__ __forceinline__ float bf2f(u16 h) {
  return __uint_as_float((unsigned)h << 16);
}
__device__ __forceinline__ unsigned pack_bf2(float a, float b) {
  union { __hip_bfloat162 h2; unsigned u; } cv;
  cv.h2 = __float22bfloat162_rn(float2{a, b});   // v_cvt_pk_bf16_f32 on gfx950
  return cv.u;
}
// async global->LDS, 16B per lane. LDS dest is wave-uniform base + lane*16.
__device__ __forceinline__ void cp16(const void* g, void* l) {
  __builtin_amdgcn_global_load_lds(
      (const __attribute__((address_space(1))) unsigned*)(uintptr_t)g,
      (__attribute__((address_space(3))) unsigned*)(unsigned)(uintptr_t)l, 16, 0, 0);
}

// ---------------- fp32 -> bf16 cast ----------------
struct CastArgs { const float* src[5]; u16* dst[5]; int n[5]; };

__global__ __launch_bounds__(256) void cast_kernel(CastArgs a) {
  const int z = blockIdx.y;
  const int i = (blockIdx.x * 256 + threadIdx.x) * 8;
  if (i >= a.n[z]) return;
  const float4* s = (const float4*)(a.src[z] + i);
  float4 v0 = s[0], v1 = s[1];
  short8 r;
  r[0] = (short)f2bf(v0.x); r[1] = (short)f2bf(v0.y);
  r[2] = (short)f2bf(v0.z); r[3] = (short)f2bf(v0.w);
  r[4] = (short)f2bf(v1.x); r[5] = (short)f2bf(v1.y);
  r[6] = (short)f2bf(v1.z); r[7] = (short)f2bf(v1.w);
  *(short8*)(a.dst[z] + i) = r;
}

// ---------------- bf16 MFMA GEMM (R7-PROVEN, LOCKED): LDS double-buffered A+B ----------------
// GEMM experiment history: R5 single-buffer 84.5us -> R7 LDS-dbuf 64us (best, benched 2x) ->
// R9 all-register flatmm 97.5us (half-round prefetch distance) -> R10 hybrid A-LDS/B-reg 77.6us
// (vmcnt(0)-before-s_barrier drains the B register prefetch issued the same round — barrier
// semantics defeat register prefetch distance; replicates guide m131-m141). LOCKED at R7.
// 128x128 tile, BK=32, 256 thr = 4 waves (2x2 of 64x64), 16x16x32 MFMA.
// LDS chunk-major [4][128][8]: frag ds_read_b128 lane stride 16B.
// modes 2b/z: 0 = bf16 row-major, 1 = bf16 per-head transposed (Vt), 2 = fp32.
// NO fused epilogue math (R4: acc scratch-spill, WRITE 24MB->1.65GB).
struct GemmArgs { const u16* A; const u16* W[3]; void* out[3]; int modes; };

__global__ __launch_bounds__(256) void gemm_mfma(GemmArgs g) {
  __shared__ __align__(16) u16 As[2][4096];
  __shared__ __align__(16) u16 Bs[2][4096];
  const int tid = threadIdx.x, lane = tid & 63, w = tid >> 6;
  const int wr = w >> 1, wc = w & 1;
  const int z = blockIdx.z;
  const u16* __restrict__ A = g.A;
  const u16* __restrict__ W = g.W[z];
  const int m0 = blockIdx.y * 128, n0 = blockIdx.x * 128;

  const f32x4 fzero = {0.f, 0.f, 0.f, 0.f};
  f32x4 acc[4][4];
  #pragma unroll
  for (int i = 0; i < 4; i++)
    #pragma unroll
    for (int j = 0; j < 4; j++) acc[i][j] = fzero;

  const int c0 = tid >> 7;
  const int rs = tid & 127;
  const int fq = (lane >> 4) * 2048;
  const int fr = (lane & 15) * 16;

  const u16* Arow = A + (size_t)(m0 + rs) * 1024;
  const u16* Wrow = W + (size_t)(n0 + rs) * 1024;

  cp16(Arow + c0 * 8,       (char*)As[0] + w * 1024);
  cp16(Arow + (c0 + 2) * 8, (char*)As[0] + 4096 + w * 1024);
  cp16(Wrow + c0 * 8,       (char*)Bs[0] + w * 1024);
  cp16(Wrow + (c0 + 2) * 8, (char*)Bs[0] + 4096 + w * 1024);
  __syncthreads();

  for (int kt = 0; kt < 32; kt++) {
    const int cur = kt & 1, nxt = cur ^ 1;
    if (kt < 31) {
      const int k1 = (kt + 1) * 32;
      cp16(Arow + k1 + c0 * 8,       (char*)As[nxt] + w * 1024);
      cp16(Arow + k1 + (c0 + 2) * 8, (char*)As[nxt] + 4096 + w * 1024);
      cp16(Wrow + k1 + c0 * 8,       (char*)Bs[nxt] + w * 1024);
      cp16(Wrow + k1 + (c0 + 2) * 8, (char*)Bs[nxt] + 4096 + w * 1024);
    }

    short8 af[4], bf_[4];
    #pragma unroll
    for (int mt = 0; mt < 4; mt++)
      af[mt] = *(const short8*)((const char*)As[cur] + fq + (wr * 64 + mt * 16) * 16 + fr);
    #pragma unroll
    for (int nt = 0; nt < 4; nt++)
      bf_[nt] = *(const short8*)((const char*)Bs[cur] + fq + (wc * 64 + nt * 16) * 16 + fr);
    #pragma unroll
    for (int mt = 0; mt < 4; mt++)
      #pragma unroll
      for (int nt = 0; nt < 4; nt++)
        acc[mt][nt] = __builtin_amdgcn_mfma_f32_16x16x32_bf16(af[mt], bf_[nt], acc[mt][nt], 0, 0, 0);
    __syncthreads();
  }

  const int mode = (g.modes >> (2 * z)) & 3;
  const int rbase = m0 + wr * 64 + (lane >> 4) * 4;
  const int cbase = n0 + wc * 64 + (lane & 15);
  if (mode == 0) {
    u16* O = (u16*)g.out[z];
    #pragma unroll
    for (int mt = 0; mt < 4; mt++)
      #pragma unroll
      for (int nt = 0; nt < 4; nt++)
        #pragma unroll
        for (int r = 0; r < 4; r++)
          O[(size_t)(rbase + mt * 16 + r) * 1024 + cbase + nt * 16] = f2bf(acc[mt][nt][r]);
  } else if (mode == 1) {
    u16* O = (u16*)g.out[z];
    #pragma unroll
    for (int mt = 0; mt < 4; mt++)
      #pragma unroll
      for (int nt = 0; nt < 4; nt++) {
        int gr = rbase + mt * 16;
        int b = gr >> 11, s0 = gr & (S_ - 1);
        int gc = cbase + nt * 16;
        int h = gc >> 6, d = gc & 63;
        ushort4 v;
        v.x = f2bf(acc[mt][nt][0]); v.y = f2bf(acc[mt][nt][1]);
        v.z = f2bf(acc[mt][nt][2]); v.w = f2bf(acc[mt][nt][3]);
        *(ushort4*)&O[(size_t)((b * 16 + h) * 64 + d) * 2048 + s0] = v;
      }
  } else {
    float* O = (float*)g.out[z];
    #pragma unroll
    for (int mt = 0; mt < 4; mt++)
      #pragma unroll
      for (int nt = 0; nt < 4; nt++)
        #pragma unroll
        for (int r = 0; r < 4; r++)
          O[(size_t)(rbase + mt * 16 + r) * 1024 + cbase + nt * 16] = acc[mt][nt][r];
  }
}

// ---------------- RoPE in-place on bf16 q/k; q PRE-SCALED by 0.125*log2(e) ----------------
__global__ __launch_bounds__(256) void rope_kernel(u16* qb, u16* kb, const int* __restrict__ tp) {
  const int isq = (blockIdx.y == 0);
  u16* p = isq ? qb : kb;
  const float outscale = isq ? 0.18033688011112042f : 1.0f;   // 0.125 * log2(e)
  const int i = (blockIdx.x * 256 + threadIdx.x) * 8;
  const int s = (i >> 10) & (S_ - 1);
  const int d = i & 63;
  const float pos = (float)tp[s];
  short8 v = *(short8*)(p + i);
  #pragma unroll
  for (int j = 0; j < 4; j++) {
    float inv = exp2f(-(float)(d + 2 * j) * 0.20762050593046439f);  // log2(10000)/64
    float phi = pos * inv;
    float sn, cs;
    sincosf(phi, &sn, &cs);
    float xe = bf2f((u16)v[2 * j]), xo = bf2f((u16)v[2 * j + 1]);
    v[2 * j]     = (short)f2bf((xe * cs - xo * sn) * outscale);
    v[2 * j + 1] = (short)f2bf((xe * sn + xo * cs) * outscale);
  }
  *(short8*)(p + i) = v;
}

// ---------------- MFMA flash attention v4 (R7-proven): paired q-tiles, 8-wave blocks ----------------
__global__ __launch_bounds__(512, 4) void attn_mfma(const u16* __restrict__ qb, const u16* __restrict__ kb,
                                                    const u16* __restrict__ vt, u16* __restrict__ ab) {
  __shared__ __align__(16) u16 Qs[2][4096];
  __shared__ __align__(16) u16 Ks[2][4096];
  __shared__ __align__(16) u16 Vs[2][4096];

  const int tid = threadIdx.x, lane = tid & 63, w = tid >> 6;
  const int v = w & 3, g = w >> 2;
  const int t = lane & 15, u = lane >> 4;
  const int bh = blockIdx.y, b = bh >> 4, h = bh & 15;
  const int i = blockIdx.x;              // 0..15
  const int qa = 31 - i;                 // tile A (long)
  const int qbt = i;                     // tile B (short)
  const int nk = 32 - i;                 // K/V stream length in 64-key tiles
  const size_t qkb = (size_t)b * S_ * 1024 + h * 64;
  const size_t vtb = (size_t)bh * 64 * 2048;

  {
    const int qtile = g ? qbt : qa;
    cp16(qb + qkb + (size_t)(qtile * 64 + lane) * 1024 + v * 8,       (char*)Qs[g] + v * 1024);
    cp16(qb + qkb + (size_t)(qtile * 64 + lane) * 1024 + (v + 4) * 8, (char*)Qs[g] + 4096 + v * 1024);
  }
  cp16(kb + qkb + (size_t)lane * 1024 + w * 8, (char*)Ks[0] + w * 1024);
  cp16(vt + vtb + (size_t)lane * 2048 + w * 8, (char*)Vs[0] + w * 1024);
  __syncthreads();

  short8 aqA[2], aqP[2];
  #pragma unroll
  for (int ks = 0; ks < 2; ks++) {
    aqA[ks] = *(const short8*)((const char*)Qs[0] + (ks * 4 + u) * 1024 + (v * 16 + t) * 16);
    short8 bq = *(const short8*)((const char*)Qs[1] + (ks * 4 + u) * 1024 + (v * 16 + t) * 16);
    aqP[ks] = g ? bq : aqA[ks];
  }

  const f32x4 fzero = {0.f, 0.f, 0.f, 0.f};
  f32x4 oPrim[4], oSec[4];
  #pragma unroll
  for (int ct = 0; ct < 4; ct++) { oPrim[ct] = fzero; oSec[ct] = fzero; }
  float rsumP = 0.f, rsumS = 0.f;

  const int qprim = g ? qbt : qa;
  const int qrowP = qprim * 64 + v * 16 + t;
  const int qrowA = qa * 64 + v * 16 + t;

  for (int kt = 0; kt < nk; kt++) {
    const int cur = kt & 1, nxt = cur ^ 1;
    if (kt + 1 < nk) {
      cp16(kb + qkb + (size_t)((kt + 1) * 64 + lane) * 1024 + w * 8, (char*)Ks[nxt] + w * 1024);
      cp16(vt + vtb + (size_t)lane * 2048 + (kt + 1) * 64 + w * 8,   (char*)Vs[nxt] + w * 1024);
    }

    if (kt <= qbt) {
      f32x4 st[4] = {fzero, fzero, fzero, fzero};
      #pragma unroll
      for (int ks = 0; ks < 2; ks++)
        #pragma unroll
        for (int ct = 0; ct < 4; ct++) {
          short8 kf = *(const short8*)((const char*)Ks[cur] + (ks * 4 + u) * 1024 + (ct * 16 + t) * 16);
          st[ct] = __builtin_amdgcn_mfma_f32_16x16x32_bf16(kf, aqP[ks], st[ct], 0, 0, 0);
        }

      unsigned pb2[4][2];
      const bool diag = (kt == qprim);
      #pragma unroll
      for (int ct = 0; ct < 4; ct++) {
        float p[4];
        #pragma unroll
        for (int r = 0; r < 4; r++) {
          int key = kt * 64 + ct * 16 + 4 * u + r;
          float pv = exp2f(st[ct][r]);
          p[r] = (diag && key > qrowP) ? 0.f : pv;
          rsumP += p[r];
        }
        pb2[ct][0] = pack_bf2(p[0], p[1]);
        pb2[ct][1] = pack_bf2(p[2], p[3]);
      }

      #pragma unroll
      for (int ks = 0; ks < 2; ks++) {
        union { short8 s8; int i4[4]; } pf;
        #pragma unroll
        for (int jj = 0; jj < 4; jj++) {
          int src = 32 * (u & 1) + 16 * (jj >> 1) + t;
          int v0 = __shfl((int)pb2[ks * 2][jj & 1], src, 64);
          int v1 = __shfl((int)pb2[ks * 2 + 1][jj & 1], src, 64);
          pf.i4[jj] = (u >> 1) ? v1 : v0;
        }
        #pragma unroll
        for (int ct = 0; ct < 4; ct++) {
          short8 vf = *(const short8*)((const char*)Vs[cur] + (ks * 4 + u) * 1024 + (ct * 16 + t) * 16);
          oPrim[ct] = __builtin_amdgcn_mfma_f32_16x16x32_bf16(vf, pf.s8, oPrim[ct], 0, 0, 0);
        }
      }
    } else {
      f32x4 st2[2] = {fzero, fzero};
      #pragma unroll
      for (int ks = 0; ks < 2; ks++)
        #pragma unroll
        for (int c = 0; c < 2; c++) {
          short8 kf = *(const short8*)((const char*)Ks[cur] + (ks * 4 + u) * 1024 + ((2 * g + c) * 16 + t) * 16);
          st2[c] = __builtin_amdgcn_mfma_f32_16x16x32_bf16(kf, aqA[ks], st2[c], 0, 0, 0);
        }

      unsigned ph[2][2];
      float rs = 0.f;
      const bool diag = (kt == qa);
      #pragma unroll
      for (int c = 0; c < 2; c++) {
        float p[4];
        #pragma unroll
        for (int r = 0; r < 4; r++) {
          int key = kt * 64 + (2 * g + c) * 16 + 4 * u + r;
          float pv = exp2f(st2[c][r]);
          p[r] = (diag && key > qrowA) ? 0.f : pv;
          rs += p[r];
        }
        ph[c][0] = pack_bf2(p[0], p[1]);
        ph[c][1] = pack_bf2(p[2], p[3]);
      }

      union { short8 s8; int i4[4]; } pf;
      #pragma unroll
      for (int jj = 0; jj < 4; jj++) {
        int src = 32 * (u & 1) + 16 * (jj >> 1) + t;
        int v0 = __shfl((int)ph[0][jj & 1], src, 64);
        int v1 = __shfl((int)ph[1][jj & 1], src, 64);
        pf.i4[jj] = (u >> 1) ? v1 : v0;
      }
      if (g) {
        rsumS += rs;
        #pragma unroll
        for (int ct = 0; ct < 4; ct++) {
          short8 vf = *(const short8*)((const char*)Vs[cur] + (4 + u) * 1024 + (ct * 16 + t) * 16);
          oSec[ct] = __builtin_amdgcn_mfma_f32_16x16x32_bf16(vf, pf.s8, oSec[ct], 0, 0, 0);
        }
      } else {
        rsumP += rs;
        #pragma unroll
        for (int ct = 0; ct < 4; ct++) {
          short8 vf = *(const short8*)((const char*)Vs[cur] + u * 1024 + (ct * 16 + t) * 16);
          oPrim[ct] = __builtin_amdgcn_mfma_f32_16x16x32_bf16(vf, pf.s8, oPrim[ct], 0, 0, 0);
        }
      }
    }
    __syncthreads();
  }

  // ---- epilogue ----
  float* dmpO = (float*)Ks;
  float* dmpR = (float*)Vs;
  if (g) {
    #pragma unroll
    for (int ct = 0; ct < 4; ct++)
      *(f32x4*)&dmpO[(size_t)(v * 64 + lane) * 16 + ct * 4] = oSec[ct];
    dmpR[v * 64 + lane] = rsumS;
    float rs = rsumP;
    rs += __shfl_xor(rs, 16, 64);
    rs += __shfl_xor(rs, 32, 64);
    const float inv = 1.0f / rs;
    #pragma unroll
    for (int ct = 0; ct < 4; ct++) {
      ushort4 vv;
      vv.x = f2bf(oPrim[ct][0] * inv); vv.y = f2bf(oPrim[ct][1] * inv);
      vv.z = f2bf(oPrim[ct][2] * inv); vv.w = f2bf(oPrim[ct][3] * inv);
      *(ushort4*)&ab[((size_t)b * S_ + qrowP) * 1024 + h * 64 + ct * 16 + 4 * u] = vv;
    }
  }
  __syncthreads();
  if (!g) {
    #pragma unroll
    for (int ct = 0; ct < 4; ct++) {
      f32x4 add = *(const f32x4*)&dmpO[(size_t)(v * 64 + lane) * 16 + ct * 4];
      oPrim[ct] += add;
    }
    float rs = rsumP + dmpR[v * 64 + lane];
    rs += __shfl_xor(rs, 16, 64);
    rs += __shfl_xor(rs, 32, 64);
    const float inv = 1.0f / rs;
    #pragma unroll
    for (int ct = 0; ct < 4; ct++) {
      ushort4 vv;
      vv.x = f2bf(oPrim[ct][0] * inv); vv.y = f2bf(oPrim[ct][1] * inv);
      vv.z = f2bf(oPrim[ct][2] * inv); vv.w = f2bf(oPrim[ct][3] * inv);
      *(ushort4*)&ab[((size_t)b * S_ + qrowA) * 1024 + h * 64 + ct * 16 + 4 * u] = vv;
    }
  }
}

extern "C" void kernel_launch(void* const* d_in, const int* in_sizes, int n_in,
                              void* d_out, int out_size, void* d_ws, size_t ws_size,
                              hipStream_t stream) {
  const float* x  = (const float*)d_in[0];
  const float* Wq = (const float*)d_in[1];
  const float* Wk = (const float*)d_in[2];
  const float* Wv = (const float*)d_in[3];
  const float* Wo = (const float*)d_in[4];
  const int*   tp = (const int*)d_in[5];
  float* out = (float*)d_out;

  char* ws = (char*)d_ws;
  u16* xb  = (u16*)(ws);                       // 8 MB
  u16* wqb = (u16*)(ws + (8 << 20));           // 2 MB each
  u16* wkb = (u16*)(ws + (10 << 20));
  u16* wvb = (u16*)(ws + (12 << 20));
  u16* wob = (u16*)(ws + (14 << 20));
  u16* qbuf = (u16*)(ws + (16 << 20));         // 8 MB
  u16* kbuf = (u16*)(ws + (24 << 20));
  u16* vtb  = (u16*)(ws + (32 << 20));
  u16* abuf = (u16*)(ws + (40 << 20));

  CastArgs ca;
  ca.src[0] = x;  ca.dst[0] = xb;  ca.n[0] = 2 * S_ * DM_;
  ca.src[1] = Wq; ca.dst[1] = wqb; ca.n[1] = DM_ * DM_;
  ca.src[2] = Wk; ca.dst[2] = wkb; ca.n[2] = DM_ * DM_;
  ca.src[3] = Wv; ca.dst[3] = wvb; ca.n[3] = DM_ * DM_;
  ca.src[4] = Wo; ca.dst[4] = wob; ca.n[4] = DM_ * DM_;
  cast_kernel<<<dim3(2048, 5), 256, 0, stream>>>(ca);

  GemmArgs gq;
  gq.A = xb;
  gq.W[0] = wqb; gq.W[1] = wkb; gq.W[2] = wvb;
  gq.out[0] = qbuf; gq.out[1] = kbuf; gq.out[2] = vtb;
  gq.modes = (1 << 4);                         // z0,z1: bf16; z2: Vt
  gemm_mfma<<<dim3(8, 32, 3), 256, 0, stream>>>(gq);

  rope_kernel<<<dim3(2048, 2), 256, 0, stream>>>(qbuf, kbuf, tp);

  attn_mfma<<<dim3(16, 32), 512, 0, stream>>>(qbuf, kbuf, vtb, abuf);

  GemmArgs go;
  go.A = abuf;
  go.W[0] = wob; go.W[1] = wob; go.W[2] = wob;
  go.out[0] = out; go.out[1] = out; go.out[2] = out;
  go.modes = 2;                                // fp32 out
  gemm_mfma<<<dim3(8, 32, 1), 256, 0, stream>>>(go);
}